// Round 5
// baseline (210.446 us; speedup 1.0000x reference)
//
#include <hip/hip_runtime.h>
#include <hip/hip_bf16.h>

#define B_ 2
#define N_ 2048
#define C_ 1024
#define H_ 16
#define HD_ 64

#define KT 64            // key tile width per flash iteration
#define KSTR 72          // K LDS row stride (64 + 8 pad)
#define VSTR 72          // Vt LDS row stride (XOR block swizzle)
#define PSTR 72          // P LDS row stride
#define NW 4             // waves per block
#define QB 128           // q rows per block (each wave owns 32)

typedef short s16x8 __attribute__((ext_vector_type(8)));
typedef short s16x4 __attribute__((ext_vector_type(4)));
typedef float f32x4 __attribute__((ext_vector_type(4)));

__device__ __forceinline__ ushort f2bf(float x) {
    __hip_bfloat16 h = __float2bfloat16(x);
    return *reinterpret_cast<ushort*>(&h);
}

__device__ __forceinline__ s16x8 cvt8(float4 a, float4 b) {
    union { s16x8 v; __hip_bfloat162 h[4]; } u;
    u.h[0] = __float22bfloat162_rn(float2{a.x, a.y});
    u.h[1] = __float22bfloat162_rn(float2{a.z, a.w});
    u.h[2] = __float22bfloat162_rn(float2{b.x, b.y});
    u.h[3] = __float22bfloat162_rn(float2{b.z, b.w});
    return u.v;
}

// ---- prepass: bit-pack mask. 8192 waves x 16 independent words.
__global__ __launch_bounds__(256)
void pack_mask(const int* __restrict__ M, unsigned long long* __restrict__ bits) {
    const int gw   = (blockIdx.x * 256 + threadIdx.x) >> 6;
    const int lane = threadIdx.x & 63;
#pragma unroll
    for (int it = 0; it < 16; ++it) {
        const size_t wi = (size_t)gw * 16 + it;
        unsigned long long bal = __ballot(M[wi * 64 + lane] != 0);
        if (lane == 0) bits[wi] = bal;
    }
}

__global__ __launch_bounds__(256, 2)
void mha_fwd(const float* __restrict__ Q, const float* __restrict__ K,
             const float* __restrict__ V, const unsigned* __restrict__ bits,
             float* __restrict__ O) {
    __shared__ ushort Kl[KT * KSTR];         // 64 keys x 64 d, bf16
    __shared__ ushort Vt[HD_ * VSTR];        // 64 d x 64 keys (block-swizzled)
    __shared__ ushort Pl[NW][32 * PSTR];     // per-wave P tile: 32 q x 64 keys

    const int qt   = blockIdx.x;
    const int h    = blockIdx.y;
    const int b    = blockIdx.z;
    const int tid  = threadIdx.x;
    const int w    = tid >> 6;       // wave id 0..3
    const int lane = tid & 63;
    const int l16  = lane & 15;
    const int quad = lane >> 4;

    const size_t head_off = (size_t)b * N_ * C_ + (size_t)h * HD_;
    const int qb = qt * QB + w * 32;             // this wave's 32 q-rows

    // Q fragments for two 16-q groups (B-operand of S^T = K Q^T);
    // fold 1/sqrt(64)*log2(e) so scores are log2-domain
    const float qs = 0.125f * 1.44269504088896f;
    s16x8 qa[2][2];
#pragma unroll
    for (int g = 0; g < 2; ++g) {
        const size_t qoff = head_off + (size_t)(qb + g * 16 + l16) * C_ + quad * 8;
        float4 q0 = *(const float4*)(Q + qoff);
        float4 q1 = *(const float4*)(Q + qoff + 4);
        float4 q2 = *(const float4*)(Q + qoff + 32);
        float4 q3 = *(const float4*)(Q + qoff + 36);
        q0.x*=qs; q0.y*=qs; q0.z*=qs; q0.w*=qs;
        q1.x*=qs; q1.y*=qs; q1.z*=qs; q1.w*=qs;
        q2.x*=qs; q2.y*=qs; q2.z*=qs; q2.w*=qs;
        q3.x*=qs; q3.y*=qs; q3.z*=qs; q3.w*=qs;
        qa[g][0] = cvt8(q0, q1);
        qa[g][1] = cvt8(q2, q3);
    }

    f32x4 acc[2][4];
#pragma unroll
    for (int g = 0; g < 2; ++g)
#pragma unroll
        for (int c = 0; c < 4; ++c) acc[g][c] = f32x4{0.f, 0.f, 0.f, 0.f};
    float lsum[2] = {0.f, 0.f};

    // K staging: 256 threads cover 64 keys x 64 d, 16 elems each
    const int skey = tid >> 2;        // 0..63
    const int sd0  = (tid & 3) * 16;  // 0,16,32,48
    // V staging: key-pairs -> conflict-free b32 writes of bf16 pairs
    const int kp   = tid >> 3;        // 0..31 key pair
    const int vd0  = (tid & 7) * 8;   // d block of 8
    const int vcol = (2 * (kp & 3)) | ((((kp >> 2) ^ (tid & 7)) & 7) << 3);

    // packed mask rows for the two q-groups (32-bit words)
    const unsigned* brow0 = bits + ((size_t)b * N_ + qb + l16) * (N_ / 32);
    const unsigned* brow1 = brow0 + (size_t)16 * (N_ / 32);

    const float SHIFT = 16.0f;        // fixed softmax shift (log2 domain)

    for (int kt = 0; kt < N_ / KT; ++kt) {
        __syncthreads();   // all readers of Kl/Vt done before restage
        {
            const size_t kbase = head_off + (size_t)(kt * KT + skey) * C_ + sd0;
            float4 k0 = *(const float4*)(K + kbase);
            float4 k1 = *(const float4*)(K + kbase + 4);
            float4 k2 = *(const float4*)(K + kbase + 8);
            float4 k3 = *(const float4*)(K + kbase + 12);
            *(s16x8*)(&Kl[skey * KSTR + sd0])     = cvt8(k0, k1);
            *(s16x8*)(&Kl[skey * KSTR + sd0 + 8]) = cvt8(k2, k3);

            const size_t vbase = head_off + (size_t)(kt * KT + 2 * kp) * C_ + vd0;
            float4 a0 = *(const float4*)(V + vbase);
            float4 a1 = *(const float4*)(V + vbase + 4);
            float4 b0 = *(const float4*)(V + vbase + C_);
            float4 b1 = *(const float4*)(V + vbase + C_ + 4);
            const float* ap = (const float*)&a0;
            const float* bp = (const float*)&b0;
#pragma unroll
            for (int i = 0; i < 4; ++i) {
                __hip_bfloat162 pr = __float22bfloat162_rn(float2{ap[i], bp[i]});
                *(unsigned*)(&Vt[(vd0 + i) * VSTR + vcol]) = *(unsigned*)&pr;
            }
            const float* aq = (const float*)&a1;
            const float* bq = (const float*)&b1;
#pragma unroll
            for (int i = 0; i < 4; ++i) {
                __hip_bfloat162 pr = __float22bfloat162_rn(float2{aq[i], bq[i]});
                *(unsigned*)(&Vt[(vd0 + 4 + i) * VSTR + vcol]) = *(unsigned*)&pr;
            }
        }
        // mask words for both q-groups, this key tile (issue before barrier)
        const unsigned m00 = brow0[2 * kt];
        const unsigned m01 = brow0[2 * kt + 1];
        const unsigned m10 = brow1[2 * kt];
        const unsigned m11 = brow1[2 * kt + 1];
        __syncthreads();

        // S^T = K Q^T : 64 keys x 16 q per group (row=key, col=qrow)
        f32x4 s[2][4];
#pragma unroll
        for (int t = 0; t < 4; ++t) {
            s16x8 kb0 = *(const s16x8*)(&Kl[(t * 16 + l16) * KSTR + quad * 8]);
            s16x8 kb1 = *(const s16x8*)(&Kl[(t * 16 + l16) * KSTR + quad * 8 + 32]);
#pragma unroll
            for (int g = 0; g < 2; ++g) {
                f32x4 z = {0.f, 0.f, 0.f, 0.f};
                z = __builtin_amdgcn_mfma_f32_16x16x32_bf16(kb0, qa[g][0], z, 0, 0, 0);
                z = __builtin_amdgcn_mfma_f32_16x16x32_bf16(kb1, qa[g][1], z, 0, 0, 0);
                s[g][t] = z;
            }
        }

        // softmax (fixed shift): lane owns qrow=l16 of each group,
        // keys t*16 + quad*4 + r
#pragma unroll
        for (int g = 0; g < 2; ++g) {
            const unsigned a0 = (g ? m10 : m00) >> (quad * 4);
            const unsigned a1 = (g ? m11 : m01) >> (quad * 4);
#pragma unroll
            for (int t = 0; t < 4; ++t) {
                const unsigned aw = (t < 2) ? a0 : a1;
                const int sh = (t & 1) * 16;
                float p0 = exp2f((((aw >> (sh + 0)) & 1u) ? s[g][t][0] : -1e9f) - SHIFT);
                float p1 = exp2f((((aw >> (sh + 1)) & 1u) ? s[g][t][1] : -1e9f) - SHIFT);
                float p2 = exp2f((((aw >> (sh + 2)) & 1u) ? s[g][t][2] : -1e9f) - SHIFT);
                float p3 = exp2f((((aw >> (sh + 3)) & 1u) ? s[g][t][3] : -1e9f) - SHIFT);
                lsum[g] += (p0 + p1) + (p2 + p3);
                union { s16x4 v; __hip_bfloat162 h[2]; } u;
                u.h[0] = __float22bfloat162_rn(float2{p0, p1});
                u.h[1] = __float22bfloat162_rn(float2{p2, p3});
                *(s16x4*)(&Pl[w][(g * 16 + l16) * PSTR + t * 16 + quad * 4]) = u.v;
            }
        }
        // per-wave LDS write->read: compiler lgkmcnt, no barrier needed

        // PV: A = P (per group), B = Vt fragments shared across groups
#pragma unroll
        for (int half = 0; half < 2; ++half) {
            s16x8 pa0 = *(const s16x8*)(&Pl[w][(l16)      * PSTR + half * 32 + quad * 8]);
            s16x8 pa1 = *(const s16x8*)(&Pl[w][(16 + l16) * PSTR + half * 32 + quad * 8]);
#pragma unroll
            for (int c = 0; c < 4; ++c) {
                const int dr  = c * 16 + l16;
                const int blk = (half * 4 + quad) ^ ((dr >> 3) & 7);
                s16x8 vb = *(const s16x8*)(&Vt[dr * VSTR + blk * 8]);
                acc[0][c] = __builtin_amdgcn_mfma_f32_16x16x32_bf16(pa0, vb, acc[0][c], 0, 0, 0);
                acc[1][c] = __builtin_amdgcn_mfma_f32_16x16x32_bf16(pa1, vb, acc[1][c], 0, 0, 0);
            }
        }
    }

    // reduce row sums across quads/halves, then epilogue per group
#pragma unroll
    for (int g = 0; g < 2; ++g) {
        lsum[g] += __shfl_xor(lsum[g], 16);
        lsum[g] += __shfl_xor(lsum[g], 32);
    }
#pragma unroll
    for (int g = 0; g < 2; ++g) {
#pragma unroll
        for (int r = 0; r < 4; ++r) {
            const float inv = 1.0f / __shfl(lsum[g], quad * 4 + r);
            const size_t obase = head_off + (size_t)(qb + g * 16 + quad * 4 + r) * C_;
            O[obase + l16]      = acc[g][0][r] * inv;
            O[obase + l16 + 16] = acc[g][1][r] * inv;
            O[obase + l16 + 32] = acc[g][2][r] * inv;
            O[obase + l16 + 48] = acc[g][3][r] * inv;
        }
    }
}

extern "C" void kernel_launch(void* const* d_in, const int* in_sizes, int n_in,
                              void* d_out, int out_size, void* d_ws, size_t ws_size,
                              hipStream_t stream) {
    const float* q = (const float*)d_in[0];
    const float* k = (const float*)d_in[1];
    const float* v = (const float*)d_in[2];
    const int*   m = (const int*)d_in[3];
    float*       o = (float*)d_out;

    hipLaunchKernelGGL(pack_mask, dim3(2048), dim3(256), 0, stream,
                       m, (unsigned long long*)d_ws);

    dim3 grid(N_ / QB, H_, B_);
    hipLaunchKernelGGL(mha_fwd, grid, dim3(256), 0, stream,
                       q, k, v, (const unsigned*)d_ws, o);
}

// Round 6
// 195.021 us; speedup vs baseline: 1.0791x; 1.0791x over previous
//
#include <hip/hip_runtime.h>
#include <hip/hip_bf16.h>

#define B_ 2
#define N_ 2048
#define C_ 1024
#define H_ 16
#define HD_ 64

#define KT 64            // key tile width per flash iteration
#define NT (N_ / KT)     // 32 tiles
#define KSTR 72          // K LDS row stride (64 + 8 pad)
#define VSTR 72          // Vt LDS row stride (XOR block swizzle)
#define PSTR 72          // P LDS row stride
#define NW 8             // waves per block
#define QB 128           // q rows per block (16 per wave)

typedef short s16x8 __attribute__((ext_vector_type(8)));
typedef short s16x4 __attribute__((ext_vector_type(4)));
typedef float f32x4 __attribute__((ext_vector_type(4)));

__device__ __forceinline__ s16x8 cvt8(float4 a, float4 b) {
    union { s16x8 v; __hip_bfloat162 h[4]; } u;
    u.h[0] = __float22bfloat162_rn(float2{a.x, a.y});
    u.h[1] = __float22bfloat162_rn(float2{a.z, a.w});
    u.h[2] = __float22bfloat162_rn(float2{b.x, b.y});
    u.h[3] = __float22bfloat162_rn(float2{b.z, b.w});
    return u.v;
}

// ---- prepass: bit-pack mask. 8192 waves x 16 independent words.
__global__ __launch_bounds__(256)
void pack_mask(const int* __restrict__ M, unsigned long long* __restrict__ bits) {
    const int gw   = (blockIdx.x * 256 + threadIdx.x) >> 6;
    const int lane = threadIdx.x & 63;
#pragma unroll
    for (int it = 0; it < 16; ++it) {
        const size_t wi = (size_t)gw * 16 + it;
        unsigned long long bal = __ballot(M[wi * 64 + lane] != 0);
        if (lane == 0) bits[wi] = bal;
    }
}

__global__ __launch_bounds__(512, 4)
void mha_fwd(const float* __restrict__ Q, const float* __restrict__ K,
             const float* __restrict__ V, const unsigned* __restrict__ bits,
             float* __restrict__ O) {
    // double-buffered K/V tiles + per-wave P tiles
    __shared__ ushort Kl[2][KT * KSTR];      // 64 keys x 64 d, bf16
    __shared__ ushort Vt[2][HD_ * VSTR];     // 64 d x 64 keys (block-swizzled)
    __shared__ ushort Pl[NW][16 * PSTR];     // per-wave P tile 16 q x 64 keys

    const int qt   = blockIdx.x;
    const int h    = blockIdx.y;
    const int b    = blockIdx.z;
    const int tid  = threadIdx.x;
    const int w    = tid >> 6;       // wave id 0..7
    const int lane = tid & 63;
    const int l16  = lane & 15;
    const int quad = lane >> 4;

    const size_t head_off = (size_t)b * N_ * C_ + (size_t)h * HD_;
    const int qb = qt * QB + w * 16;             // this wave's q-row base

    // Q fragment (B-operand of S^T = K Q^T): B[k=d=quad*8+j][n=qrow=l16]
    // fold 1/sqrt(64)*log2(e) so scores are log2-domain
    const float qs = 0.125f * 1.44269504088896f;
    const size_t qoff = head_off + (size_t)(qb + l16) * C_ + quad * 8;
    float4 q0 = *(const float4*)(Q + qoff);
    float4 q1 = *(const float4*)(Q + qoff + 4);
    float4 q2 = *(const float4*)(Q + qoff + 32);
    float4 q3 = *(const float4*)(Q + qoff + 36);
    q0.x*=qs; q0.y*=qs; q0.z*=qs; q0.w*=qs;
    q1.x*=qs; q1.y*=qs; q1.z*=qs; q1.w*=qs;
    q2.x*=qs; q2.y*=qs; q2.z*=qs; q2.w*=qs;
    q3.x*=qs; q3.y*=qs; q3.z*=qs; q3.w*=qs;
    const s16x8 qa0 = cvt8(q0, q1);
    const s16x8 qa1 = cvt8(q2, q3);

    f32x4 acc[4];
#pragma unroll
    for (int c = 0; c < 4; ++c) acc[c] = f32x4{0.f, 0.f, 0.f, 0.f};
    float lsum = 0.f;                 // per-lane partial row-sum (qrow = l16)

    // K staging: 512 threads cover 64 keys x 64 d, 8 elems each
    const int skey = tid >> 3;        // 0..63
    const int sd0  = (tid & 7) * 8;   // 0,8,...,56
    // V staging: key-pairs, 4 d's each -> conflict-free paired b32 writes
    const int kp   = tid >> 4;        // 0..31 key pair
    const int vd0  = (tid & 15) * 4;  // d block of 4 (vd0>>3 const per thread)
    const int vcol = 2 * (kp & 3) + ((((kp >> 2) ^ (vd0 >> 3)) & 7) << 3);

    // packed mask row for this lane's q-row (32-bit words)
    const unsigned* brow = bits + ((size_t)b * N_ + qb + l16) * (N_ / 32);

    const float SHIFT = 16.0f;        // fixed softmax shift (log2 domain)

    // ---- stage tile 0 into buffer 0 ----
    {
        const size_t kbase = head_off + (size_t)(skey) * C_ + sd0;
        float4 kA = *(const float4*)(K + kbase);
        float4 kB = *(const float4*)(K + kbase + 4);
        *(s16x8*)(&Kl[0][skey * KSTR + sd0]) = cvt8(kA, kB);
        const size_t vbase = head_off + (size_t)(2 * kp) * C_ + vd0;
        float4 vA = *(const float4*)(V + vbase);
        float4 vB = *(const float4*)(V + vbase + C_);
        const float* ap = (const float*)&vA;
        const float* bp = (const float*)&vB;
#pragma unroll
        for (int i = 0; i < 4; ++i) {
            __hip_bfloat162 pr = __float22bfloat162_rn(float2{ap[i], bp[i]});
            *(unsigned*)(&Vt[0][(vd0 + i) * VSTR + vcol]) = *(unsigned*)&pr;
        }
    }

    for (int kt = 0; kt < NT; ++kt) {
        const int cur = kt & 1;
        // ---- prefetch tile kt+1 (global loads in flight across compute) ----
        float4 kA, kB, vA, vB;
        const bool has_next = (kt + 1 < NT);
        if (has_next) {
            const size_t kbase = head_off + (size_t)((kt + 1) * KT + skey) * C_ + sd0;
            kA = *(const float4*)(K + kbase);
            kB = *(const float4*)(K + kbase + 4);
            const size_t vbase = head_off + (size_t)((kt + 1) * KT + 2 * kp) * C_ + vd0;
            vA = *(const float4*)(V + vbase);
            vB = *(const float4*)(V + vbase + C_);
        }
        const unsigned w0 = brow[2 * kt];
        const unsigned w1 = brow[2 * kt + 1];

        __syncthreads();   // buf[cur] staging visible; prior readers of buf[cur] done

        // S^T = K Q^T : 64 keys x 16 q (row=key, col=qrow), log2-domain
        f32x4 s[4];
#pragma unroll
        for (int t = 0; t < 4; ++t) {
            s16x8 kb0 = *(const s16x8*)(&Kl[cur][(t * 16 + l16) * KSTR + quad * 8]);
            s16x8 kb1 = *(const s16x8*)(&Kl[cur][(t * 16 + l16) * KSTR + quad * 8 + 32]);
            f32x4 z = {0.f, 0.f, 0.f, 0.f};
            z = __builtin_amdgcn_mfma_f32_16x16x32_bf16(kb0, qa0, z, 0, 0, 0);
            z = __builtin_amdgcn_mfma_f32_16x16x32_bf16(kb1, qa1, z, 0, 0, 0);
            s[t] = z;
        }

        // softmax (fixed shift): lane owns qrow=l16, keys t*16+quad*4+r
        const unsigned a0 = w0 >> (quad * 4);
        const unsigned a1 = w1 >> (quad * 4);
#pragma unroll
        for (int t = 0; t < 4; ++t) {
            const unsigned aw = (t < 2) ? a0 : a1;
            const int sh = (t & 1) * 16;
            float p0 = exp2f((((aw >> (sh + 0)) & 1u) ? s[t][0] : -1e9f) - SHIFT);
            float p1 = exp2f((((aw >> (sh + 1)) & 1u) ? s[t][1] : -1e9f) - SHIFT);
            float p2 = exp2f((((aw >> (sh + 2)) & 1u) ? s[t][2] : -1e9f) - SHIFT);
            float p3 = exp2f((((aw >> (sh + 3)) & 1u) ? s[t][3] : -1e9f) - SHIFT);
            lsum += (p0 + p1) + (p2 + p3);
            union { s16x4 v; __hip_bfloat162 h[2]; } u;
            u.h[0] = __float22bfloat162_rn(float2{p0, p1});
            u.h[1] = __float22bfloat162_rn(float2{p2, p3});
            *(s16x4*)(&Pl[w][l16 * PSTR + t * 16 + quad * 4]) = u.v;
        }
        // per-wave LDS write->read: compiler lgkmcnt, no barrier needed

        // PV: A = P (16 q x 64 keys), B = Vt (swizzled); acc row=qrow, col=d
#pragma unroll
        for (int half = 0; half < 2; ++half) {
            s16x8 pa = *(const s16x8*)(&Pl[w][l16 * PSTR + half * 32 + quad * 8]);
#pragma unroll
            for (int c = 0; c < 4; ++c) {
                const int dr  = c * 16 + l16;
                const int blk = (half * 4 + quad) ^ ((dr >> 3) & 7);
                s16x8 vb = *(const s16x8*)(&Vt[cur][dr * VSTR + blk * 8]);
                acc[c] = __builtin_amdgcn_mfma_f32_16x16x32_bf16(pa, vb, acc[c], 0, 0, 0);
            }
        }

        // ---- write prefetched tile into the other buffer ----
        if (has_next) {
            *(s16x8*)(&Kl[1 - cur][skey * KSTR + sd0]) = cvt8(kA, kB);
            const float* ap = (const float*)&vA;
            const float* bp = (const float*)&vB;
#pragma unroll
            for (int i = 0; i < 4; ++i) {
                __hip_bfloat162 pr = __float22bfloat162_rn(float2{ap[i], bp[i]});
                *(unsigned*)(&Vt[1 - cur][(vd0 + i) * VSTR + vcol]) = *(unsigned*)&pr;
            }
        }
    }

    // reduce row sums across the 4 quad-copies of each qrow
    lsum += __shfl_xor(lsum, 16);
    lsum += __shfl_xor(lsum, 32);

    // epilogue: O[qrow][d] = acc / l ; acc row = quad*4+r, col = c*16+l16
#pragma unroll
    for (int r = 0; r < 4; ++r) {
        const float inv = 1.0f / __shfl(lsum, quad * 4 + r);
        const size_t obase = head_off + (size_t)(qb + quad * 4 + r) * C_;
        O[obase + l16]      = acc[0][r] * inv;
        O[obase + l16 + 16] = acc[1][r] * inv;
        O[obase + l16 + 32] = acc[2][r] * inv;
        O[obase + l16 + 48] = acc[3][r] * inv;
    }
}

extern "C" void kernel_launch(void* const* d_in, const int* in_sizes, int n_in,
                              void* d_out, int out_size, void* d_ws, size_t ws_size,
                              hipStream_t stream) {
    const float* q = (const float*)d_in[0];
    const float* k = (const float*)d_in[1];
    const float* v = (const float*)d_in[2];
    const int*   m = (const int*)d_in[3];
    float*       o = (float*)d_out;

    hipLaunchKernelGGL(pack_mask, dim3(2048), dim3(256), 0, stream,
                       m, (unsigned long long*)d_ws);

    dim3 grid(N_ / QB, H_, B_);
    hipLaunchKernelGGL(mha_fwd, grid, dim3(512), 0, stream,
                       q, k, v, (const unsigned*)d_ws, o);
}

// Round 7
// 192.983 us; speedup vs baseline: 1.0905x; 1.0106x over previous
//
#include <hip/hip_runtime.h>
#include <hip/hip_bf16.h>

#define B_ 2
#define N_ 2048
#define C_ 1024
#define H_ 16
#define HD_ 64

#define KT 64            // key tile width per flash iteration
#define NT (N_ / KT)     // 32 tiles
#define TILE_E 4096      // elems per staged tile (64x64 bf16 = 8KB)
#define PSTR 72          // P LDS row stride
#define NW 8             // waves per block
#define QB 128           // q rows per block (16 per wave)

typedef short s16x8 __attribute__((ext_vector_type(8)));
typedef short s16x4 __attribute__((ext_vector_type(4)));
typedef float f32x4 __attribute__((ext_vector_type(4)));

__device__ __forceinline__ ushort f2bf(float x) {
    __hip_bfloat16 h = __float2bfloat16(x);
    return *reinterpret_cast<ushort*>(&h);
}

__device__ __forceinline__ s16x8 cvt8(float4 a, float4 b) {
    union { s16x8 v; __hip_bfloat162 h[4]; } u;
    u.h[0] = __float22bfloat162_rn(float2{a.x, a.y});
    u.h[1] = __float22bfloat162_rn(float2{a.z, a.w});
    u.h[2] = __float22bfloat162_rn(float2{b.x, b.y});
    u.h[3] = __float22bfloat162_rn(float2{b.z, b.w});
    return u.v;
}

// async 16B/lane global -> LDS (DMA, no VGPR round trip)
__device__ __forceinline__ void gll16(const void* g, void* l) {
    __builtin_amdgcn_global_load_lds(
        (const __attribute__((address_space(1))) unsigned*)g,
        (__attribute__((address_space(3))) unsigned*)l, 16, 0, 0);
}

// ---- prepass: bit-pack mask. 8192 waves x 16 independent words.
__global__ __launch_bounds__(256)
void pack_mask(const int* __restrict__ M, unsigned long long* __restrict__ bits) {
    const int gw   = (blockIdx.x * 256 + threadIdx.x) >> 6;
    const int lane = threadIdx.x & 63;
#pragma unroll
    for (int it = 0; it < 16; ++it) {
        const size_t wi = (size_t)gw * 16 + it;
        unsigned long long bal = __ballot(M[wi * 64 + lane] != 0);
        if (lane == 0) bits[wi] = bal;
    }
}

// ---- prepass: K fp32 -> bf16, tile-major with d-block XOR swizzle baked in.
// tile elem index: key*64 + ((db ^ (key&7))*8) + (d&7),  db = d>>3
__global__ __launch_bounds__(256)
void conv_k(const float* __restrict__ K, ushort* __restrict__ Kw) {
    const int gt = blockIdx.x * 256 + threadIdx.x;      // 0..524287
    const int b  = gt >> 18;
    const int h  = (gt >> 14) & 15;
    const int n  = (gt >> 3) & 2047;
    const int db = gt & 7;
    const size_t src = (size_t)(b * N_ + n) * C_ + h * 64 + db * 8;
    float4 f0 = *(const float4*)(K + src);
    float4 f1 = *(const float4*)(K + src + 4);
    const int key = n & 63, kt = n >> 6;
    ushort* dst = Kw + (size_t)((b * H_ + h) * NT + kt) * TILE_E
                     + key * 64 + ((db ^ (key & 7)) * 8);
    *(s16x8*)dst = cvt8(f0, f1);
}

// ---- prepass: V fp32 -> bf16 TRANSPOSED, tile-major, key-block XOR swizzle.
// tile elem index: d*64 + (((key>>3) ^ (d&7))*8) + (key&7)
__global__ __launch_bounds__(256)
void conv_v(const float* __restrict__ V, ushort* __restrict__ Vw) {
    const int gt  = blockIdx.x * 256 + threadIdx.x;     // 0..131071
    const int b   = gt >> 16;
    const int h   = (gt >> 12) & 15;
    const int kt  = (gt >> 7) & 31;
    const int kb4 = (gt >> 3) & 15;
    const int db  = gt & 7;
    const int key0 = kb4 * 4;
    float f[4][8];
#pragma unroll
    for (int i = 0; i < 4; ++i) {
        const size_t src = (size_t)(b * N_ + kt * 64 + key0 + i) * C_ + h * 64 + db * 8;
        *(float4*)&f[i][0] = *(const float4*)(V + src);
        *(float4*)&f[i][4] = *(const float4*)(V + src + 4);
    }
    ushort* tb = Vw + (size_t)((b * H_ + h) * NT + kt) * TILE_E;
#pragma unroll
    for (int j = 0; j < 8; ++j) {
        const int d = db * 8 + j;
        union { s16x4 v; __hip_bfloat162 h2[2]; } u;
        u.h2[0] = __float22bfloat162_rn(float2{f[0][j], f[1][j]});
        u.h2[1] = __float22bfloat162_rn(float2{f[2][j], f[3][j]});
        *(s16x4*)(tb + d * 64 + (((key0 >> 3) ^ (d & 7)) * 8) + (key0 & 7)) = u.v;
    }
}

// ---- main: pre-converted swizzled tiles, global_load_lds staging, 1 barrier/tile
__global__ __launch_bounds__(512, 4)
void mha_fwd(const float* __restrict__ Q, const ushort* __restrict__ Kw,
             const ushort* __restrict__ Vw, const unsigned* __restrict__ bits,
             float* __restrict__ O) {
    __shared__ ushort Kl[2][TILE_E];
    __shared__ ushort Vt[2][TILE_E];
    __shared__ ushort Pl[NW][16 * PSTR];

    const int qt   = blockIdx.x;
    const int h    = blockIdx.y;
    const int b    = blockIdx.z;
    const int tid  = threadIdx.x;
    const int w    = tid >> 6;
    const int lane = tid & 63;
    const int l16  = lane & 15;
    const int quad = lane >> 4;

    const size_t head_off = (size_t)b * N_ * C_ + (size_t)h * HD_;
    const int qb = qt * QB + w * 16;

    // Q fragment (B-operand of S^T = K Q^T); fold 1/8*log2(e): log2-domain scores
    const float qs = 0.125f * 1.44269504088896f;
    const size_t qoff = head_off + (size_t)(qb + l16) * C_ + quad * 8;
    float4 q0 = *(const float4*)(Q + qoff);
    float4 q1 = *(const float4*)(Q + qoff + 4);
    float4 q2 = *(const float4*)(Q + qoff + 32);
    float4 q3 = *(const float4*)(Q + qoff + 36);
    q0.x*=qs; q0.y*=qs; q0.z*=qs; q0.w*=qs;
    q1.x*=qs; q1.y*=qs; q1.z*=qs; q1.w*=qs;
    q2.x*=qs; q2.y*=qs; q2.z*=qs; q2.w*=qs;
    q3.x*=qs; q3.y*=qs; q3.z*=qs; q3.w*=qs;
    const s16x8 qa0 = cvt8(q0, q1);
    const s16x8 qa1 = cvt8(q2, q3);

    f32x4 acc[4];
#pragma unroll
    for (int c = 0; c < 4; ++c) acc[c] = f32x4{0.f, 0.f, 0.f, 0.f};
    float lsum = 0.f;

    // staging source pointers: lane covers bytes tid*16 of each 8KB tile
    const size_t tilebase = (size_t)((b * H_ + h) * NT) * TILE_E;
    const ushort* Kg = Kw + tilebase + (size_t)tid * 8;
    const ushort* Vg = Vw + tilebase + (size_t)tid * 8;

    const unsigned* brow = bits + ((size_t)b * N_ + qb + l16) * (N_ / 32);

    // issue tile 0 into buffer 0 (drained by first barrier)
    gll16(Kg, &Kl[0][w * 512]);
    gll16(Vg, &Vt[0][w * 512]);

    for (int kt = 0; kt < NT; ++kt) {
        const int cur = kt & 1;
        __syncthreads();   // tile kt staged; all waves done reading buf[1-cur]
        if (kt + 1 < NT) { // prefetch kt+1; flies across this tile's compute
            gll16(Kg + (size_t)(kt + 1) * TILE_E, &Kl[1 - cur][w * 512]);
            gll16(Vg + (size_t)(kt + 1) * TILE_E, &Vt[1 - cur][w * 512]);
        }
        const unsigned w0 = brow[2 * kt];
        const unsigned w1 = brow[2 * kt + 1];

        // S^T = K Q^T : 64 keys x 16 q (row=key, col=qrow), log2-domain
        f32x4 s[4];
#pragma unroll
        for (int t = 0; t < 4; ++t) {
            const int key = t * 16 + l16;
            s16x8 kb0 = *(const s16x8*)(&Kl[cur][key * 64 + ((quad ^ (key & 7)) * 8)]);
            s16x8 kb1 = *(const s16x8*)(&Kl[cur][key * 64 + (((4 + quad) ^ (key & 7)) * 8)]);
            f32x4 z = {0.f, 0.f, 0.f, 0.f};
            z = __builtin_amdgcn_mfma_f32_16x16x32_bf16(kb0, qa0, z, 0, 0, 0);
            z = __builtin_amdgcn_mfma_f32_16x16x32_bf16(kb1, qa1, z, 0, 0, 0);
            s[t] = z;
        }

        // softmax, unnormalized: p = exp2(s) (common scale cancels in O = sum pV / sum p)
        const unsigned a0 = w0 >> (quad * 4);
        const unsigned a1 = w1 >> (quad * 4);
#pragma unroll
        for (int t = 0; t < 4; ++t) {
            const unsigned aw = (t < 2) ? a0 : a1;
            const int sh = (t & 1) * 16;
            float p0 = exp2f(((aw >> (sh + 0)) & 1u) ? s[t][0] : -1e9f);
            float p1 = exp2f(((aw >> (sh + 1)) & 1u) ? s[t][1] : -1e9f);
            float p2 = exp2f(((aw >> (sh + 2)) & 1u) ? s[t][2] : -1e9f);
            float p3 = exp2f(((aw >> (sh + 3)) & 1u) ? s[t][3] : -1e9f);
            lsum += (p0 + p1) + (p2 + p3);
            union { s16x4 v; __hip_bfloat162 h2[2]; } u;
            u.h2[0] = __float22bfloat162_rn(float2{p0, p1});
            u.h2[1] = __float22bfloat162_rn(float2{p2, p3});
            *(s16x4*)(&Pl[w][l16 * PSTR + t * 16 + quad * 4]) = u.v;
        }
        // per-wave LDS write->read: compiler lgkmcnt, no barrier needed

        // PV: A = P (16 q x 64 keys), B = Vt (baked swizzle)
#pragma unroll
        for (int half = 0; half < 2; ++half) {
            s16x8 pa = *(const s16x8*)(&Pl[w][l16 * PSTR + half * 32 + quad * 8]);
#pragma unroll
            for (int c = 0; c < 4; ++c) {
                const int dr = c * 16 + l16;
                s16x8 vb = *(const s16x8*)(&Vt[cur][dr * 64 + (((half * 4 + quad) ^ (dr & 7)) * 8)]);
                acc[c] = __builtin_amdgcn_mfma_f32_16x16x32_bf16(pa, vb, acc[c], 0, 0, 0);
            }
        }
    }

    lsum += __shfl_xor(lsum, 16);
    lsum += __shfl_xor(lsum, 32);

#pragma unroll
    for (int r = 0; r < 4; ++r) {
        const float inv = 1.0f / __shfl(lsum, quad * 4 + r);
        const size_t obase = head_off + (size_t)(qb + quad * 4 + r) * C_;
        O[obase + l16]      = acc[0][r] * inv;
        O[obase + l16 + 16] = acc[1][r] * inv;
        O[obase + l16 + 32] = acc[2][r] * inv;
        O[obase + l16 + 48] = acc[3][r] * inv;
    }
}

// ================== fallback (R6 verbatim): used if ws_size too small =========
#define KSTR 72
#define VSTR 72
__global__ __launch_bounds__(512, 4)
void mha_fwd_fb(const float* __restrict__ Q, const float* __restrict__ K,
                const float* __restrict__ V, const unsigned* __restrict__ bits,
                float* __restrict__ O) {
    __shared__ ushort Kl[2][KT * KSTR];
    __shared__ ushort Vt[2][HD_ * VSTR];
    __shared__ ushort Pl[NW][16 * PSTR];
    const int qt = blockIdx.x, h = blockIdx.y, b = blockIdx.z, tid = threadIdx.x;
    const int w = tid >> 6, lane = tid & 63, l16 = lane & 15, quad = lane >> 4;
    const size_t head_off = (size_t)b * N_ * C_ + (size_t)h * HD_;
    const int qb = qt * QB + w * 16;
    const float qs = 0.125f * 1.44269504088896f;
    const size_t qoff = head_off + (size_t)(qb + l16) * C_ + quad * 8;
    float4 q0 = *(const float4*)(Q + qoff);
    float4 q1 = *(const float4*)(Q + qoff + 4);
    float4 q2 = *(const float4*)(Q + qoff + 32);
    float4 q3 = *(const float4*)(Q + qoff + 36);
    q0.x*=qs; q0.y*=qs; q0.z*=qs; q0.w*=qs;
    q1.x*=qs; q1.y*=qs; q1.z*=qs; q1.w*=qs;
    q2.x*=qs; q2.y*=qs; q2.z*=qs; q2.w*=qs;
    q3.x*=qs; q3.y*=qs; q3.z*=qs; q3.w*=qs;
    const s16x8 qa0 = cvt8(q0, q1);
    const s16x8 qa1 = cvt8(q2, q3);
    f32x4 acc[4];
#pragma unroll
    for (int c = 0; c < 4; ++c) acc[c] = f32x4{0.f, 0.f, 0.f, 0.f};
    float lsum = 0.f;
    const int skey = tid >> 3, sd0 = (tid & 7) * 8;
    const int kp = tid >> 4, vd0 = (tid & 15) * 4;
    const int vcol = 2 * (kp & 3) + ((((kp >> 2) ^ (vd0 >> 3)) & 7) << 3);
    const unsigned* brow = bits + ((size_t)b * N_ + qb + l16) * (N_ / 32);
    const float SHIFT = 16.0f;
    {
        const size_t kbase = head_off + (size_t)skey * C_ + sd0;
        float4 kA = *(const float4*)(K + kbase);
        float4 kB = *(const float4*)(K + kbase + 4);
        *(s16x8*)(&Kl[0][skey * KSTR + sd0]) = cvt8(kA, kB);
        const size_t vbase = head_off + (size_t)(2 * kp) * C_ + vd0;
        float4 vA = *(const float4*)(V + vbase);
        float4 vB = *(const float4*)(V + vbase + C_);
        const float* ap = (const float*)&vA;
        const float* bp = (const float*)&vB;
#pragma unroll
        for (int i = 0; i < 4; ++i) {
            __hip_bfloat162 pr = __float22bfloat162_rn(float2{ap[i], bp[i]});
            *(unsigned*)(&Vt[0][(vd0 + i) * VSTR + vcol]) = *(unsigned*)&pr;
        }
    }
    for (int kt = 0; kt < NT; ++kt) {
        const int cur = kt & 1;
        float4 kA, kB, vA, vB;
        const bool has_next = (kt + 1 < NT);
        if (has_next) {
            const size_t kbase = head_off + (size_t)((kt + 1) * KT + skey) * C_ + sd0;
            kA = *(const float4*)(K + kbase);
            kB = *(const float4*)(K + kbase + 4);
            const size_t vbase = head_off + (size_t)((kt + 1) * KT + 2 * kp) * C_ + vd0;
            vA = *(const float4*)(V + vbase);
            vB = *(const float4*)(V + vbase + C_);
        }
        const unsigned w0 = brow[2 * kt];
        const unsigned w1 = brow[2 * kt + 1];
        __syncthreads();
        f32x4 s[4];
#pragma unroll
        for (int t = 0; t < 4; ++t) {
            s16x8 kb0 = *(const s16x8*)(&Kl[cur][(t * 16 + l16) * KSTR + quad * 8]);
            s16x8 kb1 = *(const s16x8*)(&Kl[cur][(t * 16 + l16) * KSTR + quad * 8 + 32]);
            f32x4 z = {0.f, 0.f, 0.f, 0.f};
            z = __builtin_amdgcn_mfma_f32_16x16x32_bf16(kb0, qa0, z, 0, 0, 0);
            z = __builtin_amdgcn_mfma_f32_16x16x32_bf16(kb1, qa1, z, 0, 0, 0);
            s[t] = z;
        }
        const unsigned a0 = w0 >> (quad * 4);
        const unsigned a1 = w1 >> (quad * 4);
#pragma unroll
        for (int t = 0; t < 4; ++t) {
            const unsigned aw = (t < 2) ? a0 : a1;
            const int sh = (t & 1) * 16;
            float p0 = exp2f((((aw >> (sh + 0)) & 1u) ? s[t][0] : -1e9f) - SHIFT);
            float p1 = exp2f((((aw >> (sh + 1)) & 1u) ? s[t][1] : -1e9f) - SHIFT);
            float p2 = exp2f((((aw >> (sh + 2)) & 1u) ? s[t][2] : -1e9f) - SHIFT);
            float p3 = exp2f((((aw >> (sh + 3)) & 1u) ? s[t][3] : -1e9f) - SHIFT);
            lsum += (p0 + p1) + (p2 + p3);
            union { s16x4 v; __hip_bfloat162 h2[2]; } u;
            u.h2[0] = __float22bfloat162_rn(float2{p0, p1});
            u.h2[1] = __float22bfloat162_rn(float2{p2, p3});
            *(s16x4*)(&Pl[w][l16 * PSTR + t * 16 + quad * 4]) = u.v;
        }
#pragma unroll
        for (int half = 0; half < 2; ++half) {
            s16x8 pa = *(const s16x8*)(&Pl[w][l16 * PSTR + half * 32 + quad * 8]);
#pragma unroll
            for (int c = 0; c < 4; ++c) {
                const int dr = c * 16 + l16;
                const int blk = (half * 4 + quad) ^ ((dr >> 3) & 7);
                s16x8 vb = *(const s16x8*)(&Vt[cur][dr * VSTR + blk * 8]);
                acc[c] = __builtin_amdgcn_mfma_f32_16x16x32_bf16(pa, vb, acc[c], 0, 0, 0);
            }
        }
        if (has_next) {
            *(s16x8*)(&Kl[1 - cur][skey * KSTR + sd0]) = cvt8(kA, kB);
            const float* ap = (const float*)&vA;
            const float* bp = (const float*)&vB;
#pragma unroll
            for (int i = 0; i < 4; ++i) {
                __hip_bfloat162 pr = __float22bfloat162_rn(float2{ap[i], bp[i]});
                *(unsigned*)(&Vt[1 - cur][(vd0 + i) * VSTR + vcol]) = *(unsigned*)&pr;
            }
        }
    }
    lsum += __shfl_xor(lsum, 16);
    lsum += __shfl_xor(lsum, 32);
#pragma unroll
    for (int r = 0; r < 4; ++r) {
        const float inv = 1.0f / __shfl(lsum, quad * 4 + r);
        const size_t obase = head_off + (size_t)(qb + quad * 4 + r) * C_;
        O[obase + l16]      = acc[0][r] * inv;
        O[obase + l16 + 16] = acc[1][r] * inv;
        O[obase + l16 + 32] = acc[2][r] * inv;
        O[obase + l16 + 48] = acc[3][r] * inv;
    }
}

extern "C" void kernel_launch(void* const* d_in, const int* in_sizes, int n_in,
                              void* d_out, int out_size, void* d_ws, size_t ws_size,
                              hipStream_t stream) {
    const float* q = (const float*)d_in[0];
    const float* k = (const float*)d_in[1];
    const float* v = (const float*)d_in[2];
    const int*   m = (const int*)d_in[3];
    float*       o = (float*)d_out;

    const size_t BITS_BYTES = (size_t)B_ * N_ * N_ / 8;          // 1 MiB
    const size_t KV_BYTES   = (size_t)B_ * H_ * N_ * HD_ * 2;    // 8.39 MB each
    const size_t NEED       = BITS_BYTES + 2 * KV_BYTES;

    unsigned long long* bits = (unsigned long long*)d_ws;
    hipLaunchKernelGGL(pack_mask, dim3(2048), dim3(256), 0, stream, m, bits);

    dim3 grid(N_ / QB, H_, B_);
    if (ws_size >= NEED) {
        ushort* kw = (ushort*)((char*)d_ws + BITS_BYTES);
        ushort* vw = (ushort*)((char*)d_ws + BITS_BYTES + KV_BYTES);
        hipLaunchKernelGGL(conv_k, dim3(2048), dim3(256), 0, stream, k, kw);
        hipLaunchKernelGGL(conv_v, dim3(512), dim3(256), 0, stream, v, vw);
        hipLaunchKernelGGL(mha_fwd, grid, dim3(512), 0, stream,
                           q, kw, vw, (const unsigned*)bits, o);
    } else {
        hipLaunchKernelGGL(mha_fwd_fb, grid, dim3(512), 0, stream,
                           q, k, v, (const unsigned*)bits, o);
    }
}

// Round 8
// 185.406 us; speedup vs baseline: 1.1351x; 1.0409x over previous
//
#include <hip/hip_runtime.h>
#include <hip/hip_bf16.h>

#define B_ 2
#define N_ 2048
#define C_ 1024
#define H_ 16
#define HD_ 64

#define KT 64            // key tile width per flash iteration
#define NT (N_ / KT)     // 32 tiles
#define TILE_E 4096      // elems per staged tile (64x64 bf16 = 8KB)
#define PSTR 72          // P LDS row stride
#define NW 8             // waves per block
#define QB 128           // q rows per block (16 per wave)

typedef short s16x8 __attribute__((ext_vector_type(8)));
typedef short s16x4 __attribute__((ext_vector_type(4)));
typedef float f32x4 __attribute__((ext_vector_type(4)));

__device__ __forceinline__ ushort f2bf(float x) {
    __hip_bfloat16 h = __float2bfloat16(x);
    return *reinterpret_cast<ushort*>(&h);
}

__device__ __forceinline__ s16x8 cvt8(float4 a, float4 b) {
    union { s16x8 v; __hip_bfloat162 h[4]; } u;
    u.h[0] = __float22bfloat162_rn(float2{a.x, a.y});
    u.h[1] = __float22bfloat162_rn(float2{a.z, a.w});
    u.h[2] = __float22bfloat162_rn(float2{b.x, b.y});
    u.h[3] = __float22bfloat162_rn(float2{b.z, b.w});
    return u.v;
}

// async 16B/lane global -> LDS (DMA, no VGPR round trip)
__device__ __forceinline__ void gll16(const void* g, void* l) {
    __builtin_amdgcn_global_load_lds(
        (const __attribute__((address_space(1))) unsigned*)g,
        (__attribute__((address_space(3))) unsigned*)l, 16, 0, 0);
}

// ---- prepass: bit-pack mask. 8192 waves x 16 independent words.
__global__ __launch_bounds__(256)
void pack_mask(const int* __restrict__ M, unsigned long long* __restrict__ bits) {
    const int gw   = (blockIdx.x * 256 + threadIdx.x) >> 6;
    const int lane = threadIdx.x & 63;
#pragma unroll
    for (int it = 0; it < 16; ++it) {
        const size_t wi = (size_t)gw * 16 + it;
        unsigned long long bal = __ballot(M[wi * 64 + lane] != 0);
        if (lane == 0) bits[wi] = bal;
    }
}

// ---- prepass: K fp32 -> bf16, tile-major with d-block XOR swizzle baked in.
__global__ __launch_bounds__(256)
void conv_k(const float* __restrict__ K, ushort* __restrict__ Kw) {
    const int gt = blockIdx.x * 256 + threadIdx.x;
    const int b  = gt >> 18;
    const int h  = (gt >> 14) & 15;
    const int n  = (gt >> 3) & 2047;
    const int db = gt & 7;
    const size_t src = (size_t)(b * N_ + n) * C_ + h * 64 + db * 8;
    float4 f0 = *(const float4*)(K + src);
    float4 f1 = *(const float4*)(K + src + 4);
    const int key = n & 63, kt = n >> 6;
    ushort* dst = Kw + (size_t)((b * H_ + h) * NT + kt) * TILE_E
                     + key * 64 + ((db ^ (key & 7)) * 8);
    *(s16x8*)dst = cvt8(f0, f1);
}

// ---- prepass: V fp32 -> bf16 TRANSPOSED, tile-major, key-block XOR swizzle.
__global__ __launch_bounds__(256)
void conv_v(const float* __restrict__ V, ushort* __restrict__ Vw) {
    const int gt  = blockIdx.x * 256 + threadIdx.x;
    const int b   = gt >> 16;
    const int h   = (gt >> 12) & 15;
    const int kt  = (gt >> 7) & 31;
    const int kb4 = (gt >> 3) & 15;
    const int db  = gt & 7;
    const int key0 = kb4 * 4;
    float f[4][8];
#pragma unroll
    for (int i = 0; i < 4; ++i) {
        const size_t src = (size_t)(b * N_ + kt * 64 + key0 + i) * C_ + h * 64 + db * 8;
        *(float4*)&f[i][0] = *(const float4*)(V + src);
        *(float4*)&f[i][4] = *(const float4*)(V + src + 4);
    }
    ushort* tb = Vw + (size_t)((b * H_ + h) * NT + kt) * TILE_E;
#pragma unroll
    for (int j = 0; j < 8; ++j) {
        const int d = db * 8 + j;
        union { s16x4 v; __hip_bfloat162 h2[2]; } u;
        u.h2[0] = __float22bfloat162_rn(float2{f[0][j], f[1][j]});
        u.h2[1] = __float22bfloat162_rn(float2{f[2][j], f[3][j]});
        *(s16x4*)(tb + d * 64 + (((key0 >> 3) ^ (d & 7)) * 8) + (key0 & 7)) = u.v;
    }
}

// ---- main: unroll x2 (compile-time buffer), hoisted fragment bases
__global__ __launch_bounds__(512, 4)
void mha_fwd(const float* __restrict__ Q, const ushort* __restrict__ Kw,
             const ushort* __restrict__ Vw, const unsigned* __restrict__ bits,
             float* __restrict__ O) {
    __shared__ ushort Kl[2][TILE_E];
    __shared__ ushort Vt[2][TILE_E];
    __shared__ ushort Pl[NW][16 * PSTR];

    const int qt   = blockIdx.x;
    const int h    = blockIdx.y;
    const int b    = blockIdx.z;
    const int tid  = threadIdx.x;
    const int w    = tid >> 6;
    const int lane = tid & 63;
    const int l16  = lane & 15;
    const int quad = lane >> 4;

    const size_t head_off = (size_t)b * N_ * C_ + (size_t)h * HD_;
    const int qb = qt * QB + w * 16;

    // Q fragment (B-operand of S^T = K Q^T); fold 1/8*log2(e): log2-domain scores
    const float qs = 0.125f * 1.44269504088896f;
    const size_t qoff = head_off + (size_t)(qb + l16) * C_ + quad * 8;
    float4 q0 = *(const float4*)(Q + qoff);
    float4 q1 = *(const float4*)(Q + qoff + 4);
    float4 q2 = *(const float4*)(Q + qoff + 32);
    float4 q3 = *(const float4*)(Q + qoff + 36);
    q0.x*=qs; q0.y*=qs; q0.z*=qs; q0.w*=qs;
    q1.x*=qs; q1.y*=qs; q1.z*=qs; q1.w*=qs;
    q2.x*=qs; q2.y*=qs; q2.z*=qs; q2.w*=qs;
    q3.x*=qs; q3.y*=qs; q3.z*=qs; q3.w*=qs;
    const s16x8 qa0 = cvt8(q0, q1);
    const s16x8 qa1 = cvt8(q2, q3);

    f32x4 acc[4];
#pragma unroll
    for (int c = 0; c < 4; ++c) acc[c] = f32x4{0.f, 0.f, 0.f, 0.f};
    float2 ls2 = {0.f, 0.f};          // packed partial row-sums

    // hoisted fragment element bases (loop-invariant):
    // K/V fragment: fbase + t*1024 (K, ^64B for hi d-half) / + c*1024 (V, ^64B for hi key-half)
    const int fbase  = l16 * 64 + ((quad ^ (l16 & 7)) * 8);
    const int pwbase = l16 * PSTR + quad * 4;   // P writes at + t*16
    const int prbase = l16 * PSTR + quad * 8;   // P reads  at + half*32

    // staging pointers: lane covers bytes tid*16 of each 8KB tile
    const size_t tilebase = (size_t)((b * H_ + h) * NT) * TILE_E;
    const ushort* Kg = Kw + tilebase + (size_t)tid * 8;
    const ushort* Vg = Vw + tilebase + (size_t)tid * 8;

    const unsigned* mq = bits + ((size_t)b * N_ + qb + l16) * (N_ / 32);

    // issue tile 0 into buffer 0 (drained by first barrier)
    gll16(Kg, &Kl[0][w * 512]);
    gll16(Vg, &Vt[0][w * 512]);
    const ushort* Kg_pf = Kg + TILE_E;
    const ushort* Vg_pf = Vg + TILE_E;

    for (int kt2 = 0; kt2 < NT; kt2 += 2) {
        // mask words for both halves: one 16B load
        const uint4 mw = *(const uint4*)mq;  mq += 4;
        const bool pf1 = (kt2 + 2 < NT);
#pragma unroll
        for (int u = 0; u < 2; ++u) {        // u == buffer index (compile-time)
            __syncthreads();   // tile staged; all waves done reading other buf
            if (u == 0 || pf1) {             // prefetch next tile into other buf
                gll16(Kg_pf, &Kl[1 - u][w * 512]);
                gll16(Vg_pf, &Vt[1 - u][w * 512]);
                Kg_pf += TILE_E;  Vg_pf += TILE_E;
            }
            const unsigned w0 = u ? mw.z : mw.x;
            const unsigned w1 = u ? mw.w : mw.y;

            // S^T = K Q^T : 64 keys x 16 q (row=key, col=qrow), log2-domain
            f32x4 s[4];
#pragma unroll
            for (int t = 0; t < 4; ++t) {
                s16x8 kb0 = *(const s16x8*)(&Kl[u][fbase + t * 1024]);
                s16x8 kb1 = *(const s16x8*)(&Kl[u][(fbase ^ 32) + t * 1024]);
                f32x4 z = {0.f, 0.f, 0.f, 0.f};
                z = __builtin_amdgcn_mfma_f32_16x16x32_bf16(kb0, qa0, z, 0, 0, 0);
                z = __builtin_amdgcn_mfma_f32_16x16x32_bf16(kb1, qa1, z, 0, 0, 0);
                s[t] = z;
            }

            // softmax, unnormalized: p = exp2(s); common scale cancels in O
            const unsigned a0 = w0 >> (quad * 4);
            const unsigned a1 = w1 >> (quad * 4);
#pragma unroll
            for (int t = 0; t < 4; ++t) {
                const unsigned aw = (t < 2) ? a0 : a1;
                const int sh = (t & 1) * 16;
                float p0 = exp2f(((aw >> (sh + 0)) & 1u) ? s[t][0] : -1e9f);
                float p1 = exp2f(((aw >> (sh + 1)) & 1u) ? s[t][1] : -1e9f);
                float p2 = exp2f(((aw >> (sh + 2)) & 1u) ? s[t][2] : -1e9f);
                float p3 = exp2f(((aw >> (sh + 3)) & 1u) ? s[t][3] : -1e9f);
                ls2.x += p0 + p2;
                ls2.y += p1 + p3;
                union { s16x4 v; __hip_bfloat162 h2[2]; } uu;
                uu.h2[0] = __float22bfloat162_rn(float2{p0, p1});
                uu.h2[1] = __float22bfloat162_rn(float2{p2, p3});
                *(s16x4*)(&Pl[w][pwbase + t * 16]) = uu.v;
            }
            // per-wave LDS write->read: compiler lgkmcnt, no barrier needed

            // PV: A = P (16 q x 64 keys), B = Vt (baked swizzle)
#pragma unroll
            for (int half = 0; half < 2; ++half) {
                s16x8 pa = *(const s16x8*)(&Pl[w][prbase + half * 32]);
#pragma unroll
                for (int c = 0; c < 4; ++c) {
                    const int vidx = (half ? (fbase ^ 32) : fbase) + c * 1024;
                    s16x8 vb = *(const s16x8*)(&Vt[u][vidx]);
                    acc[c] = __builtin_amdgcn_mfma_f32_16x16x32_bf16(pa, vb, acc[c], 0, 0, 0);
                }
            }
        }
    }

    float lsum = ls2.x + ls2.y;
    lsum += __shfl_xor(lsum, 16);
    lsum += __shfl_xor(lsum, 32);

#pragma unroll
    for (int r = 0; r < 4; ++r) {
        const float inv = 1.0f / __shfl(lsum, quad * 4 + r);
        const size_t obase = head_off + (size_t)(qb + quad * 4 + r) * C_;
        O[obase + l16]      = acc[0][r] * inv;
        O[obase + l16 + 16] = acc[1][r] * inv;
        O[obase + l16 + 32] = acc[2][r] * inv;
        O[obase + l16 + 48] = acc[3][r] * inv;
    }
}

// ================== fallback (R6 verbatim): used if ws_size too small =========
#define KSTR 72
#define VSTR 72
__global__ __launch_bounds__(512, 4)
void mha_fwd_fb(const float* __restrict__ Q, const float* __restrict__ K,
                const float* __restrict__ V, const unsigned* __restrict__ bits,
                float* __restrict__ O) {
    __shared__ ushort Kl[2][KT * KSTR];
    __shared__ ushort Vt[2][HD_ * VSTR];
    __shared__ ushort Pl[NW][16 * PSTR];
    const int qt = blockIdx.x, h = blockIdx.y, b = blockIdx.z, tid = threadIdx.x;
    const int w = tid >> 6, lane = tid & 63, l16 = lane & 15, quad = lane >> 4;
    const size_t head_off = (size_t)b * N_ * C_ + (size_t)h * HD_;
    const int qb = qt * QB + w * 16;
    const float qs = 0.125f * 1.44269504088896f;
    const size_t qoff = head_off + (size_t)(qb + l16) * C_ + quad * 8;
    float4 q0 = *(const float4*)(Q + qoff);
    float4 q1 = *(const float4*)(Q + qoff + 4);
    float4 q2 = *(const float4*)(Q + qoff + 32);
    float4 q3 = *(const float4*)(Q + qoff + 36);
    q0.x*=qs; q0.y*=qs; q0.z*=qs; q0.w*=qs;
    q1.x*=qs; q1.y*=qs; q1.z*=qs; q1.w*=qs;
    q2.x*=qs; q2.y*=qs; q2.z*=qs; q2.w*=qs;
    q3.x*=qs; q3.y*=qs; q3.z*=qs; q3.w*=qs;
    const s16x8 qa0 = cvt8(q0, q1);
    const s16x8 qa1 = cvt8(q2, q3);
    f32x4 acc[4];
#pragma unroll
    for (int c = 0; c < 4; ++c) acc[c] = f32x4{0.f, 0.f, 0.f, 0.f};
    float lsum = 0.f;
    const int skey = tid >> 3, sd0 = (tid & 7) * 8;
    const int kp = tid >> 4, vd0 = (tid & 15) * 4;
    const int vcol = 2 * (kp & 3) + ((((kp >> 2) ^ (vd0 >> 3)) & 7) << 3);
    const unsigned* brow = bits + ((size_t)b * N_ + qb + l16) * (N_ / 32);
    const float SHIFT = 16.0f;
    {
        const size_t kbase = head_off + (size_t)skey * C_ + sd0;
        float4 kA = *(const float4*)(K + kbase);
        float4 kB = *(const float4*)(K + kbase + 4);
        *(s16x8*)(&Kl[0][skey * KSTR + sd0]) = cvt8(kA, kB);
        const size_t vbase = head_off + (size_t)(2 * kp) * C_ + vd0;
        float4 vA = *(const float4*)(V + vbase);
        float4 vB = *(const float4*)(V + vbase + C_);
        const float* ap = (const float*)&vA;
        const float* bp = (const float*)&vB;
#pragma unroll
        for (int i = 0; i < 4; ++i) {
            __hip_bfloat162 pr = __float22bfloat162_rn(float2{ap[i], bp[i]});
            *(unsigned*)(&Vt[0][(vd0 + i) * VSTR + vcol]) = *(unsigned*)&pr;
        }
    }
    for (int kt = 0; kt < NT; ++kt) {
        const int cur = kt & 1;
        float4 kA, kB, vA, vB;
        const bool has_next = (kt + 1 < NT);
        if (has_next) {
            const size_t kbase = head_off + (size_t)((kt + 1) * KT + skey) * C_ + sd0;
            kA = *(const float4*)(K + kbase);
            kB = *(const float4*)(K + kbase + 4);
            const size_t vbase = head_off + (size_t)((kt + 1) * KT + 2 * kp) * C_ + vd0;
            vA = *(const float4*)(V + vbase);
            vB = *(const float4*)(V + vbase + C_);
        }
        const unsigned w0 = brow[2 * kt];
        const unsigned w1 = brow[2 * kt + 1];
        __syncthreads();
        f32x4 s[4];
#pragma unroll
        for (int t = 0; t < 4; ++t) {
            s16x8 kb0 = *(const s16x8*)(&Kl[cur][(t * 16 + l16) * KSTR + quad * 8]);
            s16x8 kb1 = *(const s16x8*)(&Kl[cur][(t * 16 + l16) * KSTR + quad * 8 + 32]);
            f32x4 z = {0.f, 0.f, 0.f, 0.f};
            z = __builtin_amdgcn_mfma_f32_16x16x32_bf16(kb0, qa0, z, 0, 0, 0);
            z = __builtin_amdgcn_mfma_f32_16x16x32_bf16(kb1, qa1, z, 0, 0, 0);
            s[t] = z;
        }
        const unsigned a0 = w0 >> (quad * 4);
        const unsigned a1 = w1 >> (quad * 4);
#pragma unroll
        for (int t = 0; t < 4; ++t) {
            const unsigned aw = (t < 2) ? a0 : a1;
            const int sh = (t & 1) * 16;
            float p0 = exp2f((((aw >> (sh + 0)) & 1u) ? s[t][0] : -1e9f) - SHIFT);
            float p1 = exp2f((((aw >> (sh + 1)) & 1u) ? s[t][1] : -1e9f) - SHIFT);
            float p2 = exp2f((((aw >> (sh + 2)) & 1u) ? s[t][2] : -1e9f) - SHIFT);
            float p3 = exp2f((((aw >> (sh + 3)) & 1u) ? s[t][3] : -1e9f) - SHIFT);
            lsum += (p0 + p1) + (p2 + p3);
            union { s16x4 v; __hip_bfloat162 h2[2]; } uu;
            uu.h2[0] = __float22bfloat162_rn(float2{p0, p1});
            uu.h2[1] = __float22bfloat162_rn(float2{p2, p3});
            *(s16x4*)(&Pl[w][l16 * PSTR + t * 16 + quad * 4]) = uu.v;
        }
#pragma unroll
        for (int half = 0; half < 2; ++half) {
            s16x8 pa = *(const s16x8*)(&Pl[w][l16 * PSTR + half * 32 + quad * 8]);
#pragma unroll
            for (int c = 0; c < 4; ++c) {
                const int dr = c * 16 + l16;
                const int blk = (half * 4 + quad) ^ ((dr >> 3) & 7);
                s16x8 vb = *(const s16x8*)(&Vt[cur][dr * VSTR + blk * 8]);
                acc[c] = __builtin_amdgcn_mfma_f32_16x16x32_bf16(pa, vb, acc[c], 0, 0, 0);
            }
        }
        if (has_next) {
            *(s16x8*)(&Kl[1 - cur][skey * KSTR + sd0]) = cvt8(kA, kB);
            const float* ap = (const float*)&vA;
            const float* bp = (const float*)&vB;
#pragma unroll
            for (int i = 0; i < 4; ++i) {
                __hip_bfloat162 pr = __float22bfloat162_rn(float2{ap[i], bp[i]});
                *(unsigned*)(&Vt[1 - cur][(vd0 + i) * VSTR + vcol]) = *(unsigned*)&pr;
            }
        }
    }
    lsum += __shfl_xor(lsum, 16);
    lsum += __shfl_xor(lsum, 32);
#pragma unroll
    for (int r = 0; r < 4; ++r) {
        const float inv = 1.0f / __shfl(lsum, quad * 4 + r);
        const size_t obase = head_off + (size_t)(qb + quad * 4 + r) * C_;
        O[obase + l16]      = acc[0][r] * inv;
        O[obase + l16 + 16] = acc[1][r] * inv;
        O[obase + l16 + 32] = acc[2][r] * inv;
        O[obase + l16 + 48] = acc[3][r] * inv;
    }
}

extern "C" void kernel_launch(void* const* d_in, const int* in_sizes, int n_in,
                              void* d_out, int out_size, void* d_ws, size_t ws_size,
                              hipStream_t stream) {
    const float* q = (const float*)d_in[0];
    const float* k = (const float*)d_in[1];
    const float* v = (const float*)d_in[2];
    const int*   m = (const int*)d_in[3];
    float*       o = (float*)d_out;

    const size_t BITS_BYTES = (size_t)B_ * N_ * N_ / 8;          // 1 MiB
    const size_t KV_BYTES   = (size_t)B_ * H_ * N_ * HD_ * 2;    // 8.39 MB each
    const size_t NEED       = BITS_BYTES + 2 * KV_BYTES;

    unsigned long long* bits = (unsigned long long*)d_ws;
    hipLaunchKernelGGL(pack_mask, dim3(2048), dim3(256), 0, stream, m, bits);

    dim3 grid(N_ / QB, H_, B_);
    if (ws_size >= NEED) {
        ushort* kw = (ushort*)((char*)d_ws + BITS_BYTES);
        ushort* vw = (ushort*)((char*)d_ws + BITS_BYTES + KV_BYTES);
        hipLaunchKernelGGL(conv_k, dim3(2048), dim3(256), 0, stream, k, kw);
        hipLaunchKernelGGL(conv_v, dim3(512), dim3(256), 0, stream, v, vw);
        hipLaunchKernelGGL(mha_fwd, grid, dim3(512), 0, stream,
                           q, kw, vw, (const unsigned*)bits, o);
    } else {
        hipLaunchKernelGGL(mha_fwd_fb, grid, dim3(512), 0, stream,
                           q, k, v, (const unsigned*)bits, o);
    }
}